// Round 1
// baseline (648.759 us; speedup 1.0000x reference)
//
#include <hip/hip_runtime.h>

typedef _Float16 half_t;
typedef _Float16 v8h __attribute__((ext_vector_type(8)));
typedef _Float16 v4h __attribute__((ext_vector_type(4)));
typedef float v4f __attribute__((ext_vector_type(4)));

#define KP 7072      // 7056 padded to multiple of 32
#define KIN 7056
#define GM 8192
#define GN 512

__device__ __forceinline__ void async16(const void* g, void* l) {
  __builtin_amdgcn_global_load_lds((const __attribute__((address_space(1))) void*)g,
                                   (__attribute__((address_space(3))) void*)l, 16, 0, 0);
}

// ---- convert x (8192x7056 f32) -> xh (8192x7072 f16, zero-padded) ----
__global__ __launch_bounds__(256) void conv_x(const float* __restrict__ x, half_t* __restrict__ xh) {
  int row = blockIdx.x;
  const float* xr = x + (long)row * KIN;
  half_t* xo = xh + (long)row * KP;
  for (int c = threadIdx.x; c < KP / 4; c += 256) {
    int k = c * 4;
    v4h o;
    if (k < KIN) {                     // KIN % 4 == 0 -> chunk fully in or out
      float4 v = *(const float4*)&xr[k];
      o[0] = (_Float16)v.x; o[1] = (_Float16)v.y;
      o[2] = (_Float16)v.z; o[3] = (_Float16)v.w;
    } else {
      o[0] = (_Float16)0.f; o[1] = (_Float16)0.f;
      o[2] = (_Float16)0.f; o[3] = (_Float16)0.f;
    }
    *(v4h*)&xo[k] = o;
  }
}

// ---- transpose+convert W1 (7056x512 f32) -> w1t (512x7072 f16, zero-padded) ----
__global__ __launch_bounds__(256) void conv_w1t(const float* __restrict__ W1, half_t* __restrict__ w1t) {
  int idx = blockIdx.x * 256 + threadIdx.x;   // 512 * 1768 = 905216 threads
  int n = idx & 511;
  int c = idx >> 9;
  int k = c * 4;
  v4h o;
  if (k < KIN) {
    o[0] = (_Float16)W1[(long)(k + 0) * GN + n];
    o[1] = (_Float16)W1[(long)(k + 1) * GN + n];
    o[2] = (_Float16)W1[(long)(k + 2) * GN + n];
    o[3] = (_Float16)W1[(long)(k + 3) * GN + n];
  } else {
    o[0] = (_Float16)0.f; o[1] = (_Float16)0.f;
    o[2] = (_Float16)0.f; o[3] = (_Float16)0.f;
  }
  *(v4h*)&w1t[(long)n * KP + k] = o;
}

// ---- small setup: extract W2[:,0:8] and precompute U = RZ*RY*RX per (layer,qubit) ----
__global__ __launch_bounds__(256) void small_setup(const float* __restrict__ W2, const float* __restrict__ qp,
                                                   float* __restrict__ w2c, float* __restrict__ umat) {
  int t = threadIdx.x;
  for (int i = t; i < 512; i += 256) {
    #pragma unroll
    for (int j = 0; j < 8; j++) w2c[i * 8 + j] = W2[i * 256 + j];
  }
  if (t < 24) {   // t = layer*8 + qubit
    float a2 = qp[t * 3 + 0] * 0.5f;
    float b2 = qp[t * 3 + 1] * 0.5f;
    float g2 = qp[t * 3 + 2] * 0.5f;
    float ca = cosf(a2), sa = sinf(a2);
    float cb = cosf(b2), sb = sinf(b2);
    float cg = cosf(g2), sg = sinf(g2);
    // RY*RX
    float m00r = cb * ca, m00i =  sb * sa;
    float m01r = -sb * ca, m01i = -cb * sa;
    float m10r =  sb * ca, m10i = -cb * sa;
    float m11r =  cb * ca, m11i = -sb * sa;
    float* u = umat + t * 8;
    // row0 *= (cg - i sg), row1 *= (cg + i sg)
    u[0] = m00r * cg + m00i * sg;  u[1] = m00i * cg - m00r * sg;
    u[2] = m01r * cg + m01i * sg;  u[3] = m01i * cg - m01r * sg;
    u[4] = m10r * cg - m10i * sg;  u[5] = m10i * cg + m10r * sg;
    u[6] = m11r * cg - m11i * sg;  u[7] = m11i * cg + m11r * sg;
  }
}

// ---- GEMM1: h = relu(xh @ w1t^T + b1), fp16 MFMA, 128x128 tile, BK=32 ----
__global__ __launch_bounds__(256) void gemm1(const half_t* __restrict__ A, const half_t* __restrict__ B,
                                             const float* __restrict__ bias, half_t* __restrict__ C) {
  __shared__ half_t Ash[128 * 32];
  __shared__ half_t Bsh[128 * 32];
  int tid = threadIdx.x;
  int lane = tid & 63;
  int wave = tid >> 6;
  int bx = blockIdx.x;
  int m0 = (bx >> 2) * 128;          // 64 M-tiles; N-tiles of same M adjacent for L2 reuse
  int n0 = (bx & 3) * 128;
  int wm = (wave & 1) * 64;
  int wn = (wave >> 1) * 64;

  const half_t* Ag0 = A + (long)(m0 + (tid >> 2)) * KP + (tid & 3) * 8;
  const half_t* Ag1 = Ag0 + 64L * KP;
  const half_t* Bg0 = B + (long)(n0 + (tid >> 2)) * KP + (tid & 3) * 8;
  const half_t* Bg1 = Bg0 + 64L * KP;
  half_t* As0 = &Ash[tid * 8];
  half_t* As1 = &Ash[(256 + tid) * 8];
  half_t* Bs0 = &Bsh[tid * 8];
  half_t* Bs1 = &Bsh[(256 + tid) * 8];

  int lrow = lane & 15;
  int lk = (lane >> 4) * 8;

  v4f acc[4][4];
  #pragma unroll
  for (int i = 0; i < 4; i++)
    #pragma unroll
    for (int j = 0; j < 4; j++)
      acc[i][j] = (v4f){0.f, 0.f, 0.f, 0.f};

  for (int k0 = 0; k0 < KP; k0 += 32) {
    async16(Ag0 + k0, As0);
    async16(Ag1 + k0, As1);
    async16(Bg0 + k0, Bs0);
    async16(Bg1 + k0, Bs1);
    asm volatile("s_waitcnt vmcnt(0)" ::: "memory");
    __syncthreads();
    v8h af[4], bf[4];
    #pragma unroll
    for (int i = 0; i < 4; i++) af[i] = *(const v8h*)&Ash[(wm + i * 16 + lrow) * 32 + lk];
    #pragma unroll
    for (int j = 0; j < 4; j++) bf[j] = *(const v8h*)&Bsh[(wn + j * 16 + lrow) * 32 + lk];
    #pragma unroll
    for (int i = 0; i < 4; i++)
      #pragma unroll
      for (int j = 0; j < 4; j++)
        acc[i][j] = __builtin_amdgcn_mfma_f32_16x16x32_f16(af[i], bf[j], acc[i][j], 0, 0, 0);
    __syncthreads();
  }

  int crow = (lane >> 4) * 4;   // C/D layout: col=lane&15, row=(lane>>4)*4+v
  #pragma unroll
  for (int j = 0; j < 4; j++) {
    int col = n0 + wn + j * 16 + lrow;
    float bv = bias[col];
    #pragma unroll
    for (int i = 0; i < 4; i++) {
      int rbase = m0 + wm + i * 16 + crow;
      #pragma unroll
      for (int v = 0; v < 4; v++) {
        float val = acc[i][j][v] + bv;
        val = fmaxf(val, 0.f);
        C[(long)(rbase + v) * GN + col] = (half_t)val;
      }
    }
  }
}

// ---- angles: feats[s][j] = tanh(h[s,:] . W2[:,j] + b2[j]) for j<8 ----
__global__ __launch_bounds__(256) void angles_kernel(const half_t* __restrict__ h, const float* __restrict__ w2c,
                                                     const float* __restrict__ b2, float* __restrict__ feats) {
  int idx = blockIdx.x * 256 + threadIdx.x;   // 65536
  int s = idx >> 3;
  int j = idx & 7;
  const half_t* hr = h + (long)s * GN;
  float acc = b2[j];
  #pragma unroll 8
  for (int i = 0; i < 512; i++) acc += (float)hr[i] * w2c[i * 8 + j];
  feats[idx] = tanhf(acc);
}

// ---- quantum sim + post-MLP: one wave per sample ----
__device__ __forceinline__ void cnot_lane(float ar[4], float ai[4], int lane, int cm, int tm) {
  bool c = (lane & cm) != 0;
  #pragma unroll
  for (int r = 0; r < 4; r++) {
    float pr = __shfl_xor(ar[r], tm);
    float pi = __shfl_xor(ai[r], tm);
    ar[r] = c ? pr : ar[r];
    ai[r] = c ? pi : ai[r];
  }
}

__device__ __forceinline__ void rot_lane(float ar[4], float ai[4], int lane, int mk, const float u[8]) {
  bool hi = (lane & mk) != 0;
  float csr = hi ? u[6] : u[0], csi = hi ? u[7] : u[1];
  float cpr = hi ? u[4] : u[2], cpi = hi ? u[5] : u[3];
  #pragma unroll
  for (int r = 0; r < 4; r++) {
    float pr = __shfl_xor(ar[r], mk);
    float pi = __shfl_xor(ai[r], mk);
    float nr = csr * ar[r] - csi * ai[r] + cpr * pr - cpi * pi;
    float ni = csr * ai[r] + csi * ar[r] + cpr * pi + cpi * pr;
    ar[r] = nr; ai[r] = ni;
  }
}

__device__ __forceinline__ void apply2(const float u[8], float& x0r, float& x0i, float& x1r, float& x1i) {
  float n0r = u[0] * x0r - u[1] * x0i + u[2] * x1r - u[3] * x1i;
  float n0i = u[0] * x0i + u[1] * x0r + u[2] * x1i + u[3] * x1r;
  float n1r = u[4] * x0r - u[5] * x0i + u[6] * x1r - u[7] * x1i;
  float n1i = u[4] * x0i + u[5] * x0r + u[6] * x1i + u[7] * x1r;
  x0r = n0r; x0i = n0i; x1r = n1r; x1i = n1i;
}

__global__ __launch_bounds__(256) void quantum_post(
    const float* __restrict__ feats, const float* __restrict__ umat,
    const float* __restrict__ W1p, const float* __restrict__ b1p,
    const float* __restrict__ W2p, const float* __restrict__ b2p,
    const float* __restrict__ W3p, const float* __restrict__ b3p,
    float* __restrict__ out) {
  __shared__ float h2s[4][128];
  int tid = threadIdx.x;
  int wave = tid >> 6, lane = tid & 63;
  int s = blockIdx.x * 4 + wave;

  // initial product state: amp(i) = prod_q v_q[bit_q(i)]   (RY(f*pi) H |0>)
  const float* f = feats + s * 8;
  float v0[8], v1[8];
  #pragma unroll
  for (int q = 0; q < 8; q++) {
    float ang = f[q] * 1.57079632679f;   // f*pi/2
    float sn, cs;
    __sincosf(ang, &sn, &cs);
    v0[q] = (cs - sn) * 0.70710678118f;
    v1[q] = (cs + sn) * 0.70710678118f;
  }
  float ar[4], ai[4];
  #pragma unroll
  for (int r = 0; r < 4; r++) {
    int i = lane * 4 + r;   // qubit w bit = bit (7-w) of i; qubits 0..5 in lane bits 5..0
    float p = 1.f;
    #pragma unroll
    for (int q = 0; q < 8; q++) p *= ((i >> (7 - q)) & 1) ? v1[q] : v0[q];
    ar[r] = p; ai[r] = 0.f;
  }

  #pragma unroll
  for (int L = 0; L < 3; L++) {
    // CNOT(0,1),(2,3),(4,5)
    cnot_lane(ar, ai, lane, 32, 16);
    cnot_lane(ar, ai, lane, 8, 4);
    cnot_lane(ar, ai, lane, 2, 1);
    // CNOT(6,7): control r-bit1, target r-bit0 -> swap a2,a3
    { float t = ar[2]; ar[2] = ar[3]; ar[3] = t; t = ai[2]; ai[2] = ai[3]; ai[3] = t; }
    // CNOT(1,2),(3,4)
    cnot_lane(ar, ai, lane, 16, 8);
    cnot_lane(ar, ai, lane, 4, 2);
    // CNOT(5,6): control lane bit0, target r-bit1 -> cond swap (a0,a2),(a1,a3)
    {
      bool c = (lane & 1) != 0;
      #pragma unroll
      for (int r = 0; r < 2; r++) {
        float t0 = ar[r], t1 = ar[r + 2];
        ar[r] = c ? t1 : t0; ar[r + 2] = c ? t0 : t1;
        t0 = ai[r]; t1 = ai[r + 2];
        ai[r] = c ? t1 : t0; ai[r + 2] = c ? t0 : t1;
      }
    }
    // rotations: qubits 0..5 (lane bits), 6,7 (register)
    #pragma unroll
    for (int q = 0; q < 6; q++) {
      float u[8];
      #pragma unroll
      for (int c = 0; c < 8; c++) u[c] = umat[(L * 8 + q) * 8 + c];
      rot_lane(ar, ai, lane, 32 >> q, u);
    }
    {
      float u[8];
      #pragma unroll
      for (int c = 0; c < 8; c++) u[c] = umat[(L * 8 + 6) * 8 + c];
      apply2(u, ar[0], ai[0], ar[2], ai[2]);
      apply2(u, ar[1], ai[1], ar[3], ai[3]);
      #pragma unroll
      for (int c = 0; c < 8; c++) u[c] = umat[(L * 8 + 7) * 8 + c];
      apply2(u, ar[0], ai[0], ar[1], ai[1]);
      apply2(u, ar[2], ai[2], ar[3], ai[3]);
    }
  }

  // expectations <Z_q>
  float p0 = ar[0] * ar[0] + ai[0] * ai[0];
  float p1 = ar[1] * ar[1] + ai[1] * ai[1];
  float p2 = ar[2] * ar[2] + ai[2] * ai[2];
  float p3 = ar[3] * ar[3] + ai[3] * ai[3];
  float psum = p0 + p1 + p2 + p3;
  float e[8];
  #pragma unroll
  for (int q = 0; q < 6; q++) e[q] = (lane & (32 >> q)) ? -psum : psum;
  e[6] = p0 + p1 - p2 - p3;
  e[7] = p0 - p1 + p2 - p3;
  #pragma unroll
  for (int m = 1; m < 64; m <<= 1)
    #pragma unroll
    for (int q = 0; q < 8; q++) e[q] += __shfl_xor(e[q], m);

  // post-MLP: h2(128) -> h3(64) -> out(6)
  float h2a = b1p[lane], h2b = b1p[lane + 64];
  #pragma unroll
  for (int k = 0; k < 8; k++) {
    h2a += e[k] * W1p[k * 128 + lane];
    h2b += e[k] * W1p[k * 128 + lane + 64];
  }
  h2s[wave][lane] = fmaxf(h2a, 0.f);
  h2s[wave][lane + 64] = fmaxf(h2b, 0.f);
  __syncthreads();
  float h3 = b2p[lane];
  #pragma unroll 8
  for (int k = 0; k < 128; k++) h3 += h2s[wave][k] * W2p[k * 64 + lane];
  h3 = fmaxf(h3, 0.f);
  float o[6];
  #pragma unroll
  for (int j = 0; j < 6; j++) o[j] = h3 * W3p[lane * 6 + j];
  #pragma unroll
  for (int m = 1; m < 64; m <<= 1)
    #pragma unroll
    for (int j = 0; j < 6; j++) o[j] += __shfl_xor(o[j], m);
  if (lane == 0) {
    #pragma unroll
    for (int j = 0; j < 6; j++) out[(long)s * 6 + j] = o[j] + b3p[j];
  }
}

extern "C" void kernel_launch(void* const* d_in, const int* in_sizes, int n_in,
                              void* d_out, int out_size, void* d_ws, size_t ws_size,
                              hipStream_t stream) {
  const float* x   = (const float*)d_in[0];
  const float* W1  = (const float*)d_in[1];
  const float* b1  = (const float*)d_in[2];
  const float* W2  = (const float*)d_in[3];
  const float* b2  = (const float*)d_in[4];
  const float* qp  = (const float*)d_in[5];
  const float* W1p = (const float*)d_in[6];
  const float* b1p = (const float*)d_in[7];
  const float* W2p = (const float*)d_in[8];
  const float* b2p = (const float*)d_in[9];
  const float* W3p = (const float*)d_in[10];
  const float* b3p = (const float*)d_in[11];
  float* out = (float*)d_out;

  char* ws = (char*)d_ws;
  half_t* xh   = (half_t*)(ws);                                 // 8192*7072*2 = 115867648
  half_t* w1t  = (half_t*)(ws + 115867648);                     // 512*7072*2  = 7241728
  half_t* h    = (half_t*)(ws + 123109376);                     // 8192*512*2  = 8388608
  float*  w2c  = (float*)(ws + 131497984);                      // 512*8*4     = 16384
  float*  feats= (float*)(ws + 131514368);                      // 8192*8*4    = 262144
  float*  umat = (float*)(ws + 131776512);                      // 24*8*4      = 768

  conv_x<<<GM, 256, 0, stream>>>(x, xh);
  conv_w1t<<<3536, 256, 0, stream>>>(W1, w1t);
  small_setup<<<1, 256, 0, stream>>>(W2, qp, w2c, umat);
  gemm1<<<256, 256, 0, stream>>>(xh, w1t, b1, h);
  angles_kernel<<<256, 256, 0, stream>>>(h, w2c, b2, feats);
  quantum_post<<<2048, 256, 0, stream>>>(feats, umat, W1p, b1p, W2p, b2p, W3p, b3p, out);
}

// Round 3
// 467.265 us; speedup vs baseline: 1.3884x; 1.3884x over previous
//
#include <hip/hip_runtime.h>

typedef _Float16 half_t;
typedef _Float16 v8h __attribute__((ext_vector_type(8)));
typedef __fp16 pk2 __attribute__((ext_vector_type(2)));   // cvt_pkrtz return type
typedef float v4f __attribute__((ext_vector_type(4)));

#define KIN 7056
#define KP 7072
#define GM 8192
#define GN 512
#define SLICE (8192L * 512)   // elements per K-split partial

__device__ __forceinline__ void async16(const void* g, void* l) {
  __builtin_amdgcn_global_load_lds((const __attribute__((address_space(1))) void*)g,
                                   (__attribute__((address_space(3))) void*)l, 16, 0, 0);
}

// ---- W1 (7056x512 f32) -> w1t (512x7072 f16, zero-padded), LDS-tiled transpose ----
__global__ __launch_bounds__(256) void conv_w1t(const float* __restrict__ W1, half_t* __restrict__ w1t) {
  __shared__ float t[32][65];
  int tid = threadIdx.x;
  int k0 = blockIdx.x * 32;       // 221 tiles cover 7072
  int n0 = blockIdx.y * 64;       // 8 tiles cover 512
  #pragma unroll
  for (int rr = 0; rr < 8; rr++) {
    int r = rr * 4 + (tid >> 6);
    int c = tid & 63;
    int k = k0 + r;
    t[r][c] = (k < KIN) ? W1[(long)k * GN + n0 + c] : 0.f;
  }
  __syncthreads();
  int n_l = tid >> 2;
  int k_l = (tid & 3) * 8;
  v8h o;
  #pragma unroll
  for (int j = 0; j < 8; j++) o[j] = (_Float16)t[k_l + j][n_l];   // RNE
  *(v8h*)&w1t[(long)(n0 + n_l) * KP + k0 + k_l] = o;
}

// ---- small setup: compact W2[:,0:8] and fused U = RZ*RY*RX per (layer,qubit) ----
__global__ __launch_bounds__(256) void small_setup(const float* __restrict__ W2, const float* __restrict__ qp,
                                                   float* __restrict__ w2c, float* __restrict__ umat) {
  int t = threadIdx.x;
  for (int i = t; i < 512; i += 256) {
    #pragma unroll
    for (int j = 0; j < 8; j++) w2c[i * 8 + j] = W2[i * 256 + j];
  }
  if (t < 24) {   // t = layer*8 + qubit
    float a2 = qp[t * 3 + 0] * 0.5f;
    float b2 = qp[t * 3 + 1] * 0.5f;
    float g2 = qp[t * 3 + 2] * 0.5f;
    float ca = cosf(a2), sa = sinf(a2);
    float cb = cosf(b2), sb = sinf(b2);
    float cg = cosf(g2), sg = sinf(g2);
    float m00r = cb * ca, m00i =  sb * sa;
    float m01r = -sb * ca, m01i = -cb * sa;
    float m10r =  sb * ca, m10i = -cb * sa;
    float m11r =  cb * ca, m11i = -sb * sa;
    float* u = umat + t * 8;
    u[0] = m00r * cg + m00i * sg;  u[1] = m00i * cg - m00r * sg;
    u[2] = m01r * cg + m01i * sg;  u[3] = m01i * cg - m01r * sg;
    u[4] = m10r * cg - m10i * sg;  u[5] = m10i * cg + m10r * sg;
    u[6] = m11r * cg - m11i * sg;  u[7] = m11i * cg + m11r * sg;
  }
}

// ---- GEMM1: K-split-3 partials P[kc] = x_f32 @ w1t^T (f16 MFMA, f32 acc), 128x128 tile ----
// grid 768: n = bid/192 (0..3), p = bid%192, kc = p%3, m = p/3  -> same (m,kc) across n are
// bids p, p+192, p+384, p+576, all congruent mod 8 -> same XCD -> A-panel served by one L2.
__global__ __launch_bounds__(256, 3) void gemm1(const float* __restrict__ A, const half_t* __restrict__ B,
                                                float* __restrict__ P) {
  __shared__ float  Ash[128 * 32];
  __shared__ half_t Bsh[128 * 32];
  int tid = threadIdx.x, lane = tid & 63, wave = tid >> 6;
  int bid = blockIdx.x;
  int n0 = (bid / 192) * 128;
  int p  = bid % 192;
  int kc = p % 3;
  int m0 = (p / 3) * 128;
  int kbeg = kc * 2368;                       // 74*32; chunks {74,74,73} steps
  int kend = (kc == 2) ? KP : kbeg + 2368;
  int wm = (wave & 1) * 64;
  int wn = (wave >> 1) * 64;
  int lrow = lane & 15;
  int lkg = lane >> 4;                        // A k-offset = lkg*8 floats

  // staging coords (XOR-swizzled on the global side; LDS side must stay base+lane*16)
  int c4 = tid & 7;          // A: 16B chunk = 4 floats, 8 chunks/row
  int rA0 = tid >> 3;        // + rr*32
  int c8 = tid & 3;          // B: 16B chunk = 8 halfs, 4 chunks/row
  int rB0 = tid >> 2;        // + rr*64
  long Arow[4]; int Asc[4];
  #pragma unroll
  for (int rr = 0; rr < 4; rr++) {
    int r = rr * 32 + rA0;
    Arow[rr] = (long)(m0 + r) * KIN;
    Asc[rr] = (c4 ^ (r & 7)) * 4;
  }
  const half_t* Bg[2];
  #pragma unroll
  for (int rr = 0; rr < 2; rr++) {
    int r = rr * 64 + rB0;
    Bg[rr] = B + (long)(n0 + r) * KP + (c8 ^ (r & 3)) * 8;
  }
  float* AsD[4]; half_t* BsD[2];
  #pragma unroll
  for (int rr = 0; rr < 4; rr++) AsD[rr] = &Ash[(rr * 256 + tid) * 4];
  #pragma unroll
  for (int rr = 0; rr < 2; rr++) BsD[rr] = &Bsh[(rr * 256 + tid) * 8];

  v4f acc[4][4];
  #pragma unroll
  for (int i = 0; i < 4; i++)
    #pragma unroll
    for (int j = 0; j < 4; j++)
      acc[i][j] = (v4f){0.f, 0.f, 0.f, 0.f};

  for (int k0 = kbeg; k0 < kend; k0 += 32) {
    #pragma unroll
    for (int rr = 0; rr < 4; rr++) {
      int col = k0 + Asc[rr];
      col = col > 7052 ? 7052 : col;          // pad cols read valid junk; B pad is zero
      async16(A + Arow[rr] + col, AsD[rr]);
    }
    #pragma unroll
    for (int rr = 0; rr < 2; rr++) async16(Bg[rr] + k0, BsD[rr]);
    asm volatile("s_waitcnt vmcnt(0)" ::: "memory");
    __syncthreads();

    v8h af[4], bf[4];
    #pragma unroll
    for (int i = 0; i < 4; i++) {
      int row = wm + i * 16 + lrow;
      int sw = row & 7;
      int c4a = lkg * 2;
      v4f lo = *(const v4f*)&Ash[row * 32 + ((c4a ^ sw) * 4)];
      v4f hi = *(const v4f*)&Ash[row * 32 + (((c4a + 1) ^ sw) * 4)];
      union { v8h v; pk2 h[4]; } u;
      u.h[0] = __builtin_amdgcn_cvt_pkrtz(lo[0], lo[1]);
      u.h[1] = __builtin_amdgcn_cvt_pkrtz(lo[2], lo[3]);
      u.h[2] = __builtin_amdgcn_cvt_pkrtz(hi[0], hi[1]);
      u.h[3] = __builtin_amdgcn_cvt_pkrtz(hi[2], hi[3]);
      af[i] = u.v;
    }
    #pragma unroll
    for (int j = 0; j < 4; j++) {
      int row = wn + j * 16 + lrow;
      bf[j] = *(const v8h*)&Bsh[row * 32 + ((lkg ^ (row & 3)) * 8)];
    }
    #pragma unroll
    for (int i = 0; i < 4; i++)
      #pragma unroll
      for (int j = 0; j < 4; j++)
        acc[i][j] = __builtin_amdgcn_mfma_f32_16x16x32_f16(af[i], bf[j], acc[i][j], 0, 0, 0);
    __syncthreads();
  }

  float* Pk = P + kc * SLICE;
  int crow = lkg * 4;   // C/D: col=lane&15, row=(lane>>4)*4+v
  #pragma unroll
  for (int j = 0; j < 4; j++) {
    int col = n0 + wn + j * 16 + lrow;
    #pragma unroll
    for (int i = 0; i < 4; i++) {
      int rbase = m0 + wm + i * 16 + crow;
      #pragma unroll
      for (int v = 0; v < 4; v++)
        Pk[(long)(rbase + v) * GN + col] = acc[i][j][v];
    }
  }
}

// ---- quantum sim + angles prologue + post-MLP: one wave per sample ----
__device__ __forceinline__ void cnot_lane(float ar[4], float ai[4], int lane, int cm, int tm) {
  bool c = (lane & cm) != 0;
  #pragma unroll
  for (int r = 0; r < 4; r++) {
    float pr = __shfl_xor(ar[r], tm);
    float pi = __shfl_xor(ai[r], tm);
    ar[r] = c ? pr : ar[r];
    ai[r] = c ? pi : ai[r];
  }
}

__device__ __forceinline__ void rot_lane(float ar[4], float ai[4], int lane, int mk, const float u[8]) {
  bool hi = (lane & mk) != 0;
  float csr = hi ? u[6] : u[0], csi = hi ? u[7] : u[1];
  float cpr = hi ? u[4] : u[2], cpi = hi ? u[5] : u[3];
  #pragma unroll
  for (int r = 0; r < 4; r++) {
    float pr = __shfl_xor(ar[r], mk);
    float pi = __shfl_xor(ai[r], mk);
    float nr = csr * ar[r] - csi * ai[r] + cpr * pr - cpi * pi;
    float ni = csr * ai[r] + csi * ar[r] + cpr * pi + cpi * pr;
    ar[r] = nr; ai[r] = ni;
  }
}

__device__ __forceinline__ void apply2(const float u[8], float& x0r, float& x0i, float& x1r, float& x1i) {
  float n0r = u[0] * x0r - u[1] * x0i + u[2] * x1r - u[3] * x1i;
  float n0i = u[0] * x0i + u[1] * x0r + u[2] * x1i + u[3] * x1r;
  float n1r = u[4] * x0r - u[5] * x0i + u[6] * x1r - u[7] * x1i;
  float n1i = u[4] * x0i + u[5] * x0r + u[6] * x1i + u[7] * x1r;
  x0r = n0r; x0i = n0i; x1r = n1r; x1i = n1i;
}

__global__ __launch_bounds__(256) void quantum_post(
    const float* __restrict__ P, const float* __restrict__ b1, const float* __restrict__ w2c,
    const float* __restrict__ b2, const float* __restrict__ umat,
    const float* __restrict__ W1p, const float* __restrict__ b1p,
    const float* __restrict__ W2p, const float* __restrict__ b2p,
    const float* __restrict__ W3p, const float* __restrict__ b3p,
    float* __restrict__ out) {
  __shared__ float h2s[4][128];
  int tid = threadIdx.x;
  int wave = tid >> 6, lane = tid & 63;
  int s = blockIdx.x * 4 + wave;

  // ---- angles prologue: h[k]=relu(sum_kc P + b1), a_j = h . W2[:,j], f_j = tanh(a_j+b2_j)
  long base = (long)s * GN + lane * 8;
  v4f h0 = (v4f){0.f,0.f,0.f,0.f}, h1 = h0;
  #pragma unroll
  for (int c = 0; c < 3; c++) {
    h0 += *(const v4f*)&P[c * SLICE + base];
    h1 += *(const v4f*)&P[c * SLICE + base + 4];
  }
  float hk[8];
  #pragma unroll
  for (int t = 0; t < 4; t++) hk[t]     = fmaxf(h0[t] + b1[lane * 8 + t], 0.f);
  #pragma unroll
  for (int t = 0; t < 4; t++) hk[t + 4] = fmaxf(h1[t] + b1[lane * 8 + 4 + t], 0.f);
  float a[8] = {0,0,0,0,0,0,0,0};
  const float* w2r = w2c + lane * 64;
  #pragma unroll
  for (int t = 0; t < 8; t++) {
    v4f wlo = *(const v4f*)&w2r[t * 8];
    v4f whi = *(const v4f*)&w2r[t * 8 + 4];
    #pragma unroll
    for (int j = 0; j < 4; j++) { a[j] += hk[t] * wlo[j]; a[j + 4] += hk[t] * whi[j]; }
  }
  #pragma unroll
  for (int m = 1; m < 64; m <<= 1)
    #pragma unroll
    for (int j = 0; j < 8; j++) a[j] += __shfl_xor(a[j], m);
  float f[8];
  #pragma unroll
  for (int j = 0; j < 8; j++) f[j] = tanhf(a[j] + b2[j]);

  // ---- initial product state: RY(f*pi) H |0>
  float v0[8], v1[8];
  #pragma unroll
  for (int q = 0; q < 8; q++) {
    float ang = f[q] * 1.57079632679f;
    float sn, cs;
    __sincosf(ang, &sn, &cs);
    v0[q] = (cs - sn) * 0.70710678118f;
    v1[q] = (cs + sn) * 0.70710678118f;
  }
  float ar[4], ai[4];
  #pragma unroll
  for (int r = 0; r < 4; r++) {
    int i = lane * 4 + r;   // qubit w bit = bit (7-w) of i
    float prod = 1.f;
    #pragma unroll
    for (int q = 0; q < 8; q++) prod *= ((i >> (7 - q)) & 1) ? v1[q] : v0[q];
    ar[r] = prod; ai[r] = 0.f;
  }

  #pragma unroll
  for (int L = 0; L < 3; L++) {
    cnot_lane(ar, ai, lane, 32, 16);
    cnot_lane(ar, ai, lane, 8, 4);
    cnot_lane(ar, ai, lane, 2, 1);
    { float t = ar[2]; ar[2] = ar[3]; ar[3] = t; t = ai[2]; ai[2] = ai[3]; ai[3] = t; }
    cnot_lane(ar, ai, lane, 16, 8);
    cnot_lane(ar, ai, lane, 4, 2);
    {
      bool c = (lane & 1) != 0;
      #pragma unroll
      for (int r = 0; r < 2; r++) {
        float t0 = ar[r], t1 = ar[r + 2];
        ar[r] = c ? t1 : t0; ar[r + 2] = c ? t0 : t1;
        t0 = ai[r]; t1 = ai[r + 2];
        ai[r] = c ? t1 : t0; ai[r + 2] = c ? t0 : t1;
      }
    }
    #pragma unroll
    for (int q = 0; q < 6; q++) {
      float u[8];
      #pragma unroll
      for (int c = 0; c < 8; c++) u[c] = umat[(L * 8 + q) * 8 + c];
      rot_lane(ar, ai, lane, 32 >> q, u);
    }
    {
      float u[8];
      #pragma unroll
      for (int c = 0; c < 8; c++) u[c] = umat[(L * 8 + 6) * 8 + c];
      apply2(u, ar[0], ai[0], ar[2], ai[2]);
      apply2(u, ar[1], ai[1], ar[3], ai[3]);
      #pragma unroll
      for (int c = 0; c < 8; c++) u[c] = umat[(L * 8 + 7) * 8 + c];
      apply2(u, ar[0], ai[0], ar[1], ai[1]);
      apply2(u, ar[2], ai[2], ar[3], ai[3]);
    }
  }

  float p0 = ar[0] * ar[0] + ai[0] * ai[0];
  float p1 = ar[1] * ar[1] + ai[1] * ai[1];
  float p2 = ar[2] * ar[2] + ai[2] * ai[2];
  float p3 = ar[3] * ar[3] + ai[3] * ai[3];
  float psum = p0 + p1 + p2 + p3;
  float e[8];
  #pragma unroll
  for (int q = 0; q < 6; q++) e[q] = (lane & (32 >> q)) ? -psum : psum;
  e[6] = p0 + p1 - p2 - p3;
  e[7] = p0 - p1 + p2 - p3;
  #pragma unroll
  for (int m = 1; m < 64; m <<= 1)
    #pragma unroll
    for (int q = 0; q < 8; q++) e[q] += __shfl_xor(e[q], m);

  float h2a = b1p[lane], h2b = b1p[lane + 64];
  #pragma unroll
  for (int k = 0; k < 8; k++) {
    h2a += e[k] * W1p[k * 128 + lane];
    h2b += e[k] * W1p[k * 128 + lane + 64];
  }
  h2s[wave][lane] = fmaxf(h2a, 0.f);
  h2s[wave][lane + 64] = fmaxf(h2b, 0.f);
  __syncthreads();
  float h3 = b2p[lane];
  #pragma unroll 8
  for (int k = 0; k < 128; k++) h3 += h2s[wave][k] * W2p[k * 64 + lane];
  h3 = fmaxf(h3, 0.f);
  float o[6];
  #pragma unroll
  for (int j = 0; j < 6; j++) o[j] = h3 * W3p[lane * 6 + j];
  #pragma unroll
  for (int m = 1; m < 64; m <<= 1)
    #pragma unroll
    for (int j = 0; j < 6; j++) o[j] += __shfl_xor(o[j], m);
  if (lane == 0) {
    #pragma unroll
    for (int j = 0; j < 6; j++) out[(long)s * 6 + j] = o[j] + b3p[j];
  }
}

extern "C" void kernel_launch(void* const* d_in, const int* in_sizes, int n_in,
                              void* d_out, int out_size, void* d_ws, size_t ws_size,
                              hipStream_t stream) {
  const float* x   = (const float*)d_in[0];
  const float* W1  = (const float*)d_in[1];
  const float* b1  = (const float*)d_in[2];
  const float* W2  = (const float*)d_in[3];
  const float* b2  = (const float*)d_in[4];
  const float* qp  = (const float*)d_in[5];
  const float* W1p = (const float*)d_in[6];
  const float* b1p = (const float*)d_in[7];
  const float* W2p = (const float*)d_in[8];
  const float* b2p = (const float*)d_in[9];
  const float* W3p = (const float*)d_in[10];
  const float* b3p = (const float*)d_in[11];
  float* out = (float*)d_out;

  char* ws = (char*)d_ws;
  half_t* w1t  = (half_t*)(ws);                    // 512*7072*2 = 7,241,728
  float*  w2c  = (float*)(ws + 7241728);           // 16,384
  float*  umat = (float*)(ws + 7258112);           // 768 (pad to 7,258,880)
  float*  P    = (float*)(ws + 7258880);           // 3*8192*512*4 = 50,331,648

  conv_w1t<<<dim3(221, 8), 256, 0, stream>>>(W1, w1t);
  small_setup<<<1, 256, 0, stream>>>(W2, qp, w2c, umat);
  gemm1<<<768, 256, 0, stream>>>(x, w1t, P);
  quantum_post<<<2048, 256, 0, stream>>>(P, b1, w2c, b2, umat,
                                         W1p, b1p, W2p, b2p, W3p, b3p, out);
}